// Round 1
// baseline (2308.190 us; speedup 1.0000x reference)
//
#include <hip/hip_runtime.h>
#include <hip/hip_bf16.h>
#include <stdint.h>
#include <stddef.h>

// Problem: out[M,N] = (x[M,K] @ W_q[N,K]^T) / scales[N] + bias[N]
// M = B*S = 8192, K = 4096, N = 16384. x f32, W_q int32 (int8 range).
#define M_DIM 8192
#define K_DIM 4096
#define N_DIM 16384

typedef __attribute__((ext_vector_type(8))) short short8;
typedef __attribute__((ext_vector_type(4))) float f32x4;

// f32 -> bf16 round-to-nearest-even. Exact for int8-range integers.
__device__ __forceinline__ unsigned short f2bf(float f) {
    union { float f; uint32_t u; } c; c.f = f;
    uint32_t u = c.u;
    return (unsigned short)((u + 0x7FFFu + ((u >> 16) & 1u)) >> 16);
}

// ---------------- conversion kernels (path A) ----------------

__global__ __launch_bounds__(256) void conv_x_kernel(const float* __restrict__ x,
                                                     unsigned short* __restrict__ out) {
    size_t i = ((size_t)blockIdx.x * 256 + threadIdx.x) * 8;
    const float4* p = (const float4*)(x + i);
    float4 u = p[0], v = p[1];
    short8 h;
    h[0] = (short)f2bf(u.x); h[1] = (short)f2bf(u.y);
    h[2] = (short)f2bf(u.z); h[3] = (short)f2bf(u.w);
    h[4] = (short)f2bf(v.x); h[5] = (short)f2bf(v.y);
    h[6] = (short)f2bf(v.z); h[7] = (short)f2bf(v.w);
    *(short8*)(out + i) = h;
}

__global__ __launch_bounds__(256) void conv_w_kernel(const int* __restrict__ w,
                                                     unsigned short* __restrict__ out) {
    size_t i = ((size_t)blockIdx.x * 256 + threadIdx.x) * 8;
    const int4* p = (const int4*)(w + i);
    int4 u = p[0], v = p[1];
    short8 h;
    h[0] = (short)f2bf((float)u.x); h[1] = (short)f2bf((float)u.y);
    h[2] = (short)f2bf((float)u.z); h[3] = (short)f2bf((float)u.w);
    h[4] = (short)f2bf((float)v.x); h[5] = (short)f2bf((float)v.y);
    h[6] = (short)f2bf((float)v.z); h[7] = (short)f2bf((float)v.w);
    *(short8*)(out + i) = h;
}

// ---------------- async global->LDS helper ----------------

__device__ __forceinline__ void gld_lds16(const void* g, void* l) {
    __builtin_amdgcn_global_load_lds(
        (__attribute__((address_space(1))) void*)(g),
        (__attribute__((address_space(3))) void*)(l),
        16, 0, 0);
}

// ---------------- main GEMM (path A: pre-converted bf16 inputs) ----------------
// 128x128 block tile, 4 waves (2x2), each wave 64x64 via 4x4 grid of
// mfma_f32_16x16x32_bf16. BK=64. LDS 32 KB. m97 structure.

__global__ __launch_bounds__(256) void gemm_a_kernel(
    const unsigned short* __restrict__ A,   // [M,K] bf16 (x)
    const unsigned short* __restrict__ Bm,  // [N,K] bf16 (W)
    const float* __restrict__ scales,
    const float* __restrict__ bias,
    float* __restrict__ C) {
    __shared__ unsigned short As[128 * 64];
    __shared__ unsigned short Bs[128 * 64];

    const int tid = threadIdx.x;
    const int m0 = blockIdx.y * 128;
    const int n0 = blockIdx.x * 128;
    const int lane = tid & 63;
    const int wv = tid >> 6;
    const int wm = (wv & 1) * 64;   // wave's M offset within tile
    const int wn = (wv >> 1) * 64;  // wave's N offset within tile
    const int lm = lane & 15;       // fragment row (A: m, B: n, C: col)
    const int lk = (lane >> 4) * 8; // fragment k base

    f32x4 acc[4][4] = {};

    for (int kt = 0; kt < K_DIM / 64; ++kt) {
        const int k0 = kt * 64;
        // stage A tile (128x64 bf16 = 16 KB): 1024 16B chunks, 4 per thread
#pragma unroll
        for (int i = 0; i < 4; ++i) {
            int c = tid + i * 256;
            int row = c >> 3, col = (c & 7) * 8;
            gld_lds16(A + (size_t)(m0 + row) * K_DIM + k0 + col, (char*)As + c * 16);
        }
        // stage B tile (rows of W, n-major)
#pragma unroll
        for (int i = 0; i < 4; ++i) {
            int c = tid + i * 256;
            int row = c >> 3, col = (c & 7) * 8;
            gld_lds16(Bm + (size_t)(n0 + row) * K_DIM + k0 + col, (char*)Bs + c * 16);
        }
        __syncthreads();

#pragma unroll
        for (int kk = 0; kk < 64; kk += 32) {
            short8 af[4], bfr[4];
#pragma unroll
            for (int im = 0; im < 4; ++im)
                af[im] = *(const short8*)&As[(wm + im * 16 + lm) * 64 + kk + lk];
#pragma unroll
            for (int jn = 0; jn < 4; ++jn)
                bfr[jn] = *(const short8*)&Bs[(wn + jn * 16 + lm) * 64 + kk + lk];
#pragma unroll
            for (int im = 0; im < 4; ++im)
#pragma unroll
                for (int jn = 0; jn < 4; ++jn)
                    acc[im][jn] = __builtin_amdgcn_mfma_f32_16x16x32_bf16(
                        af[im], bfr[jn], acc[im][jn], 0, 0, 0);
        }
        __syncthreads();
    }

    // epilogue: out = acc / scale[col] + bias[col]
    // C/D layout (16x16x32): col = lane&15, row = (lane>>4)*4 + reg
#pragma unroll
    for (int jn = 0; jn < 4; ++jn) {
        const int col = n0 + wn + jn * 16 + lm;
        const float inv = 1.0f / scales[col];
        const float bb = bias[col];
#pragma unroll
        for (int im = 0; im < 4; ++im) {
            const int r0 = m0 + wm + im * 16 + (lane >> 4) * 4;
#pragma unroll
            for (int r = 0; r < 4; ++r)
                C[(size_t)(r0 + r) * N_DIM + col] = acc[im][jn][r] * inv + bb;
        }
    }
}

// ---------------- fallback GEMM (path B: inline conversion, no workspace) ----------------

__global__ __launch_bounds__(256) void gemm_b_kernel(
    const float* __restrict__ X,   // [M,K] f32
    const int* __restrict__ W,     // [N,K] int32
    const float* __restrict__ scales,
    const float* __restrict__ bias,
    float* __restrict__ C) {
    __shared__ unsigned short As[128 * 64];
    __shared__ unsigned short Bs[128 * 64];

    const int tid = threadIdx.x;
    const int m0 = blockIdx.y * 128;
    const int n0 = blockIdx.x * 128;
    const int lane = tid & 63;
    const int wv = tid >> 6;
    const int wm = (wv & 1) * 64;
    const int wn = (wv >> 1) * 64;
    const int lm = lane & 15;
    const int lk = (lane >> 4) * 8;

    f32x4 acc[4][4] = {};

    for (int kt = 0; kt < K_DIM / 64; ++kt) {
        const int k0 = kt * 64;
#pragma unroll
        for (int i = 0; i < 4; ++i) {
            int c = tid + i * 256;
            int row = c >> 3, col = (c & 7) * 8;
            const float* p = X + (size_t)(m0 + row) * K_DIM + k0 + col;
            float4 u = *(const float4*)p;
            float4 v = *(const float4*)(p + 4);
            short8 h;
            h[0] = (short)f2bf(u.x); h[1] = (short)f2bf(u.y);
            h[2] = (short)f2bf(u.z); h[3] = (short)f2bf(u.w);
            h[4] = (short)f2bf(v.x); h[5] = (short)f2bf(v.y);
            h[6] = (short)f2bf(v.z); h[7] = (short)f2bf(v.w);
            *(short8*)&As[(size_t)c * 8] = h;
        }
#pragma unroll
        for (int i = 0; i < 4; ++i) {
            int c = tid + i * 256;
            int row = c >> 3, col = (c & 7) * 8;
            const int* p = W + (size_t)(n0 + row) * K_DIM + k0 + col;
            int4 u = *(const int4*)p;
            int4 v = *(const int4*)(p + 4);
            short8 h;
            h[0] = (short)f2bf((float)u.x); h[1] = (short)f2bf((float)u.y);
            h[2] = (short)f2bf((float)u.z); h[3] = (short)f2bf((float)u.w);
            h[4] = (short)f2bf((float)v.x); h[5] = (short)f2bf((float)v.y);
            h[6] = (short)f2bf((float)v.z); h[7] = (short)f2bf((float)v.w);
            *(short8*)&Bs[(size_t)c * 8] = h;
        }
        __syncthreads();

#pragma unroll
        for (int kk = 0; kk < 64; kk += 32) {
            short8 af[4], bfr[4];
#pragma unroll
            for (int im = 0; im < 4; ++im)
                af[im] = *(const short8*)&As[(wm + im * 16 + lm) * 64 + kk + lk];
#pragma unroll
            for (int jn = 0; jn < 4; ++jn)
                bfr[jn] = *(const short8*)&Bs[(wn + jn * 16 + lm) * 64 + kk + lk];
#pragma unroll
            for (int im = 0; im < 4; ++im)
#pragma unroll
                for (int jn = 0; jn < 4; ++jn)
                    acc[im][jn] = __builtin_amdgcn_mfma_f32_16x16x32_bf16(
                        af[im], bfr[jn], acc[im][jn], 0, 0, 0);
        }
        __syncthreads();
    }

#pragma unroll
    for (int jn = 0; jn < 4; ++jn) {
        const int col = n0 + wn + jn * 16 + lm;
        const float inv = 1.0f / scales[col];
        const float bb = bias[col];
#pragma unroll
        for (int im = 0; im < 4; ++im) {
            const int r0 = m0 + wm + im * 16 + (lane >> 4) * 4;
#pragma unroll
            for (int r = 0; r < 4; ++r)
                C[(size_t)(r0 + r) * N_DIM + col] = acc[im][jn][r] * inv + bb;
        }
    }
}

// ---------------- launch ----------------

extern "C" void kernel_launch(void* const* d_in, const int* in_sizes, int n_in,
                              void* d_out, int out_size, void* d_ws, size_t ws_size,
                              hipStream_t stream) {
    const float* x      = (const float*)d_in[0];  // [8192, 4096] f32
    const int*   wq     = (const int*)d_in[1];    // [16384, 4096] int32
    const float* scales = (const float*)d_in[2];  // [16384]
    const float* bias   = (const float*)d_in[3];  // [16384]
    float* out = (float*)d_out;                   // [8192, 16384] f32

    const size_t x_elems = (size_t)M_DIM * K_DIM;   // 33.5M
    const size_t w_elems = (size_t)N_DIM * K_DIM;   // 67.1M
    const size_t need = (x_elems + w_elems) * sizeof(unsigned short); // 192 MB

    dim3 grid(N_DIM / 128, M_DIM / 128);  // 128 x 64 = 8192 blocks

    if (ws_size >= need) {
        unsigned short* xbf = (unsigned short*)d_ws;
        unsigned short* wbf = xbf + x_elems;
        conv_x_kernel<<<(int)(x_elems / (256 * 8)), 256, 0, stream>>>(x, xbf);
        conv_w_kernel<<<(int)(w_elems / (256 * 8)), 256, 0, stream>>>(wq, wbf);
        gemm_a_kernel<<<grid, 256, 0, stream>>>(xbf, wbf, scales, bias, out);
    } else {
        gemm_b_kernel<<<grid, 256, 0, stream>>>(x, wq, scales, bias, out);
    }
}